// Round 2
// baseline (2750.264 us; speedup 1.0000x reference)
//
#include <hip/hip_runtime.h>
#include <math.h>

typedef _Float16 f16;
typedef unsigned short u16;
typedef unsigned int u32;
typedef __attribute__((ext_vector_type(8))) _Float16 f16x8;   // 8 f16 operand frag (4 VGPR)
typedef __attribute__((ext_vector_type(16))) float f32x16;    // 32x32 accumulator

#define LO_SCALE 4096.0f
#define LO_INV   2.44140625e-4f   // 1/4096

// ---------- f16 scaled split: x ~= h + l*(1/4096), |err| <= ~2^-22 |x| ----------
__device__ __forceinline__ void split2f(float x, f16 &h, f16 &l) {
    h = (f16)x;
    l = (f16)((x - (float)h) * LO_SCALE);
}
__device__ __forceinline__ f32x16 mfma32(f16x8 a, f16x8 b, f32x16 c) {
    return __builtin_amdgcn_mfma_f32_32x32x16_f16(a, b, c, 0, 0, 0);
}

// ---------- prep: transpose + zero-pad + hi/scaled-lo split ----------
// W [K][N] fp32 (row-major) -> Wt_hi/Wt_lo [Npad][Kpad] f16 (k contiguous)
__global__ __launch_bounds__(256) void prep_kernel(
    const float* __restrict__ W, int K, int N, int Kpad, int Npad,
    f16* __restrict__ hi, f16* __restrict__ lo)
{
    int total = Kpad * Npad;
    for (int i = blockIdx.x * blockDim.x + threadIdx.x; i < total;
         i += gridDim.x * blockDim.x) {
        int n = i / Kpad, k = i - n * Kpad;
        float w = (k < K && n < N) ? W[k * N + n] : 0.f;
        f16 h, l; split2f(w, h, l);
        hi[i] = h; lo[i] = l;
    }
}

// ---------- kernel 1: VAE decoder (21 -> 750 -> 750 -> 3, tanh) ----------
#define NW1 12
#define T1 768
constexpr int LDH1 = 776;  // 768 + 8 pad, multiple of 8

__global__ __launch_bounds__(768, 3) void dec_kernel(
    const float* __restrict__ states, const float* __restrict__ noise,
    const f16* __restrict__ w1h, const f16* __restrict__ w1l, const float* __restrict__ b1,
    const f16* __restrict__ w2h, const f16* __restrict__ w2l, const float* __restrict__ b2,
    const float* __restrict__ w3, const float* __restrict__ b3,
    float* __restrict__ adec)
{
    __shared__ float Xs[32][33];
    __shared__ __align__(16) f16 H1h[32 * LDH1];
    __shared__ __align__(16) f16 H1l[32 * LDH1];
    __shared__ float ow[NW1][32][3];

    const int tid = threadIdx.x;
    const int lane = tid & 63;
    const int wid = tid >> 6;       // 0..11
    const int l31 = lane & 31;
    const int l5  = lane >> 5;      // 0/1
    const int rowblk = blockIdx.x * 32;

    // build X = [state(11) | clip(noise)(10) | 0...] for 32 rows
    for (int idx = tid; idx < 32 * 32; idx += T1) {
        int r = idx >> 5, c = idx & 31;
        int g = rowblk + r;
        float v = 0.f;
        if (c < 11) v = states[(g / 10) * 11 + c];
        else if (c < 21) {
            float z = noise[g * 10 + (c - 11)];
            v = fminf(fmaxf(z, -0.5f), 0.5f);
        }
        Xs[r][c] = v;
    }
    __syncthreads();

    // phase 1: H1 = relu(X*W1 + b1), N=768 (24 tiles), K=32 (2 steps)
    f16x8 xah[2], xal[2];
    #pragma unroll
    for (int s = 0; s < 2; ++s) {
        #pragma unroll
        for (int r = 0; r < 8; ++r) {
            float x = Xs[l31][s * 16 + l5 * 8 + r];
            f16 h, l; split2f(x, h, l);
            xah[s][r] = h;
            xal[s][r] = l;
        }
    }
    for (int t = wid; t < 24; t += NW1) {
        f32x16 am, ac;
        #pragma unroll
        for (int r = 0; r < 16; ++r) { am[r] = 0.f; ac[r] = 0.f; }
        int n = t * 32 + l31;
        #pragma unroll
        for (int s = 0; s < 2; ++s) {
            const f16x8 bh = *(const f16x8*)&w1h[n * 32 + s * 16 + l5 * 8];
            const f16x8 bl = *(const f16x8*)&w1l[n * 32 + s * 16 + l5 * 8];
            am = mfma32(xah[s], bh, am);
            ac = mfma32(xal[s], bh, ac);
            ac = mfma32(xah[s], bl, ac);
        }
        int col = t * 32 + l31;
        float bias = (col < 750) ? b1[col] : 0.f;
        #pragma unroll
        for (int r = 0; r < 16; ++r) {
            int row = (r & 3) + 8 * (r >> 2) + 4 * l5;
            float v = fmaxf(fmaf(ac[r], LO_INV, am[r]) + bias, 0.f);
            f16 h, l; split2f(v, h, l);
            H1h[row * LDH1 + col] = h;
            H1l[row * LDH1 + col] = l;
        }
    }
    __syncthreads();

    // phase 2: H2 = relu(H1*W2 + b2), N=768 (2 tiles/wave), K=768
    f32x16 a0m, a0c, a1m, a1c;
    #pragma unroll
    for (int r = 0; r < 16; ++r) { a0m[r] = 0.f; a0c[r] = 0.f; a1m[r] = 0.f; a1c[r] = 0.f; }
    const int n0 = wid * 32 + l31;
    const int n1 = (wid + NW1) * 32 + l31;
    for (int kk = 0; kk < 768; kk += 16) {
        const f16x8 ah = *(const f16x8*)&H1h[l31 * LDH1 + kk + l5 * 8];
        const f16x8 al = *(const f16x8*)&H1l[l31 * LDH1 + kk + l5 * 8];
        const f16x8 b0h = *(const f16x8*)&w2h[n0 * 768 + kk + l5 * 8];
        const f16x8 b0l = *(const f16x8*)&w2l[n0 * 768 + kk + l5 * 8];
        const f16x8 b1h = *(const f16x8*)&w2h[n1 * 768 + kk + l5 * 8];
        const f16x8 b1l = *(const f16x8*)&w2l[n1 * 768 + kk + l5 * 8];
        a0m = mfma32(ah, b0h, a0m);
        a1m = mfma32(ah, b1h, a1m);
        a0c = mfma32(al, b0h, a0c);
        a1c = mfma32(al, b1h, a1c);
        a0c = mfma32(ah, b0l, a0c);
        a1c = mfma32(ah, b1l, a1c);
    }

    // phase 3: A = tanh(relu(H2)*W3 + b3)  (per-lane fp32 dot + shuffle tree)
    #pragma unroll
    for (int j = 0; j < 3; ++j) {
        float p[16];
        #pragma unroll
        for (int r = 0; r < 16; ++r) p[r] = 0.f;
        #pragma unroll
        for (int u = 0; u < 2; ++u) {
            int col = (wid + u * NW1) * 32 + l31;
            if (col < 750) {
                float bias = b2[col];
                float wv = w3[col * 3 + j];
                #pragma unroll
                for (int r = 0; r < 16; ++r) {
                    float hm = (u == 0) ? a0m[r] : a1m[r];
                    float hc = (u == 0) ? a0c[r] : a1c[r];
                    float h = fmaxf(fmaf(hc, LO_INV, hm) + bias, 0.f);
                    p[r] += h * wv;
                }
            }
        }
        #pragma unroll
        for (int m = 1; m < 32; m <<= 1) {
            #pragma unroll
            for (int r = 0; r < 16; ++r) p[r] += __shfl_xor(p[r], m);
        }
        if (l31 == 0) {
            #pragma unroll
            for (int r = 0; r < 16; ++r) {
                int row = (r & 3) + 8 * (r >> 2) + 4 * l5;
                ow[wid][row][j] = p[r];
            }
        }
    }
    __syncthreads();
    if (tid < 96) {
        int row = tid / 3, j = tid - row * 3;
        float s = 0.f;
        #pragma unroll
        for (int w = 0; w < NW1; ++w) s += ow[w][row][j];
        adec[(rowblk + row) * 3 + j] = tanhf(s + b3[j]);
    }
}

// ---------- kernel 2: actor + twin critics ----------
#define NW2 10
#define T2 640
constexpr int LDH2 = 456;  // 448 + 8 pad

template<int NJ>
__device__ __forceinline__ void mlp_net2(
    const f16* __restrict__ w1h, const f16* __restrict__ w1l, const float* __restrict__ b1,
    const f16* __restrict__ w2h, const f16* __restrict__ w2l, const float* __restrict__ b2,
    const float* __restrict__ w3,
    const float (*Xs)[33], f16* H1h, f16* H1l, float (*ow)[32][3],
    int tid)
{
    const int lane = tid & 63;
    const int wid = tid >> 6;       // 0..9
    const int l31 = lane & 31;
    const int l5  = lane >> 5;

    // phase 1: H1 = relu(X*W1 + b1), N=448 (14 tiles), K=32
    f16x8 xah[2], xal[2];
    #pragma unroll
    for (int s = 0; s < 2; ++s) {
        #pragma unroll
        for (int r = 0; r < 8; ++r) {
            float x = Xs[l31][s * 16 + l5 * 8 + r];
            f16 h, l; split2f(x, h, l);
            xah[s][r] = h;
            xal[s][r] = l;
        }
    }
    for (int t = wid; t < 14; t += NW2) {
        f32x16 am, ac;
        #pragma unroll
        for (int r = 0; r < 16; ++r) { am[r] = 0.f; ac[r] = 0.f; }
        int n = t * 32 + l31;
        #pragma unroll
        for (int s = 0; s < 2; ++s) {
            const f16x8 bh = *(const f16x8*)&w1h[n * 32 + s * 16 + l5 * 8];
            const f16x8 bl = *(const f16x8*)&w1l[n * 32 + s * 16 + l5 * 8];
            am = mfma32(xah[s], bh, am);
            ac = mfma32(xal[s], bh, ac);
            ac = mfma32(xah[s], bl, ac);
        }
        int col = t * 32 + l31;
        float bias = (col < 400) ? b1[col] : 0.f;
        #pragma unroll
        for (int r = 0; r < 16; ++r) {
            int row = (r & 3) + 8 * (r >> 2) + 4 * l5;
            float v = fmaxf(fmaf(ac[r], LO_INV, am[r]) + bias, 0.f);
            f16 h, l; split2f(v, h, l);
            H1h[row * LDH2 + col] = h;
            H1l[row * LDH2 + col] = l;
        }
    }
    __syncthreads();

    // phase 2: N=320 (1 tile/wave), K=448
    f32x16 a2m, a2c;
    #pragma unroll
    for (int r = 0; r < 16; ++r) { a2m[r] = 0.f; a2c[r] = 0.f; }
    const int n = wid * 32 + l31;
    for (int kk = 0; kk < 448; kk += 16) {
        const f16x8 ah = *(const f16x8*)&H1h[l31 * LDH2 + kk + l5 * 8];
        const f16x8 al = *(const f16x8*)&H1l[l31 * LDH2 + kk + l5 * 8];
        const f16x8 bh = *(const f16x8*)&w2h[n * 448 + kk + l5 * 8];
        const f16x8 bl = *(const f16x8*)&w2l[n * 448 + kk + l5 * 8];
        a2m = mfma32(ah, bh, a2m);
        a2c = mfma32(al, bh, a2c);
        a2c = mfma32(ah, bl, a2c);
    }

    // phase 3
    #pragma unroll
    for (int j = 0; j < NJ; ++j) {
        float p[16];
        #pragma unroll
        for (int r = 0; r < 16; ++r) p[r] = 0.f;
        int col = wid * 32 + l31;
        if (col < 300) {
            float bias = b2[col];
            float wv = w3[col * NJ + j];
            #pragma unroll
            for (int r = 0; r < 16; ++r) {
                float h = fmaxf(fmaf(a2c[r], LO_INV, a2m[r]) + bias, 0.f);
                p[r] += h * wv;
            }
        }
        #pragma unroll
        for (int m = 1; m < 32; m <<= 1) {
            #pragma unroll
            for (int r = 0; r < 16; ++r) p[r] += __shfl_xor(p[r], m);
        }
        if (l31 == 0) {
            #pragma unroll
            for (int r = 0; r < 16; ++r) {
                int row = (r & 3) + 8 * (r >> 2) + 4 * l5;
                ow[wid][row][j] = p[r];
            }
        }
    }
    // caller syncs before reading ow
}

__global__ __launch_bounds__(640, 5) void aq_kernel(
    const float* __restrict__ states, const float* __restrict__ adec,
    const f16* __restrict__ aw1h, const f16* __restrict__ aw1l, const float* __restrict__ ab1,
    const f16* __restrict__ aw2h, const f16* __restrict__ aw2l, const float* __restrict__ ab2,
    const float* __restrict__ aw3, const float* __restrict__ ab3,
    const f16* __restrict__ c1w1h, const f16* __restrict__ c1w1l, const float* __restrict__ c1b1,
    const f16* __restrict__ c1w2h, const f16* __restrict__ c1w2l, const float* __restrict__ c1b2,
    const float* __restrict__ c1w3, const float* __restrict__ c1b3,
    const f16* __restrict__ c2w1h, const f16* __restrict__ c2w1l, const float* __restrict__ c2b1,
    const f16* __restrict__ c2w2h, const f16* __restrict__ c2w2l, const float* __restrict__ c2b2,
    const float* __restrict__ c2w3, const float* __restrict__ c2b3,
    float* __restrict__ actions, float* __restrict__ qmin)
{
    __shared__ float Xs[32][33];
    __shared__ __align__(16) f16 H1h[32 * LDH2];
    __shared__ __align__(16) f16 H1l[32 * LDH2];
    __shared__ float ow[NW2][32][3];
    __shared__ float q1v[32];

    const int tid = threadIdx.x;
    const int rowblk = blockIdx.x * 32;

    // X = [state(11) | a_dec(3) | 0...]
    for (int idx = tid; idx < 32 * 32; idx += T2) {
        int r = idx >> 5, c = idx & 31;
        int g = rowblk + r;
        float v = 0.f;
        if (c < 11) v = states[(g / 10) * 11 + c];
        else if (c < 14) v = adec[g * 3 + (c - 11)];
        Xs[r][c] = v;
    }
    __syncthreads();

    // actor
    mlp_net2<3>(aw1h, aw1l, ab1, aw2h, aw2l, ab2, aw3, Xs, H1h, H1l, ow, tid);
    __syncthreads();
    if (tid < 96) {
        int row = tid / 3, j = tid - row * 3;
        float s = 0.f;
        #pragma unroll
        for (int w = 0; w < NW2; ++w) s += ow[w][row][j];
        float da = tanhf(s + ab3[j]);
        float ap = Xs[row][11 + j];
        float act = fminf(fmaxf(0.05f * da + ap, -1.f), 1.f);
        actions[(rowblk + row) * 3 + j] = act;
        Xs[row][11 + j] = act;
    }
    __syncthreads();

    // q1
    mlp_net2<1>(c1w1h, c1w1l, c1b1, c1w2h, c1w2l, c1b2, c1w3, Xs, H1h, H1l, ow, tid);
    __syncthreads();
    if (tid < 32) {
        float s = 0.f;
        #pragma unroll
        for (int w = 0; w < NW2; ++w) s += ow[w][tid][0];
        q1v[tid] = s + c1b3[0];
    }
    __syncthreads();

    // q2 + min
    mlp_net2<1>(c2w1h, c2w1l, c2b1, c2w2h, c2w2l, c2b2, c2w3, Xs, H1h, H1l, ow, tid);
    __syncthreads();
    if (tid < 32) {
        float s = 0.f;
        #pragma unroll
        for (int w = 0; w < NW2; ++w) s += ow[w][tid][0];
        float q2 = s + c2b3[0];
        qmin[rowblk + tid] = fminf(q1v[tid], q2);
    }
}

// ---------- kernel 3: per-state argmax (first max) + gather ----------
__global__ __launch_bounds__(256) void select_kernel(
    const float* __restrict__ qmin, const float* __restrict__ actions,
    float* __restrict__ out)
{
    int s = blockIdx.x * blockDim.x + threadIdx.x;
    if (s >= 16384) return;
    const float* q = qmin + s * 10;
    int best = 0;
    float bq = q[0];
    #pragma unroll
    for (int i = 1; i < 10; ++i) {
        float v = q[i];
        if (v > bq) { bq = v; best = i; }
    }
    const float* a = actions + (size_t)(s * 10 + best) * 3;
    out[s * 3 + 0] = a[0];
    out[s * 3 + 1] = a[1];
    out[s * 3 + 2] = a[2];
}

extern "C" void kernel_launch(void* const* d_in, const int* in_sizes, int n_in,
                              void* d_out, int out_size, void* d_ws, size_t ws_size,
                              hipStream_t stream)
{
    const float* states = (const float*)d_in[0];
    const float* noise  = (const float*)d_in[1];
    const float* dec_w1 = (const float*)d_in[2];
    const float* dec_b1 = (const float*)d_in[3];
    const float* dec_w2 = (const float*)d_in[4];
    const float* dec_b2 = (const float*)d_in[5];
    const float* dec_w3 = (const float*)d_in[6];
    const float* dec_b3 = (const float*)d_in[7];
    const float* act_w1 = (const float*)d_in[8];
    const float* act_b1 = (const float*)d_in[9];
    const float* act_w2 = (const float*)d_in[10];
    const float* act_b2 = (const float*)d_in[11];
    const float* act_w3 = (const float*)d_in[12];
    const float* act_b3 = (const float*)d_in[13];
    const float* q1_w1 = (const float*)d_in[14];
    const float* q1_b1 = (const float*)d_in[15];
    const float* q1_w2 = (const float*)d_in[16];
    const float* q1_b2 = (const float*)d_in[17];
    const float* q1_w3 = (const float*)d_in[18];
    const float* q1_b3 = (const float*)d_in[19];
    const float* q2_w1 = (const float*)d_in[20];
    const float* q2_b1 = (const float*)d_in[21];
    const float* q2_w2 = (const float*)d_in[22];
    const float* q2_b2 = (const float*)d_in[23];
    const float* q2_w3 = (const float*)d_in[24];
    const float* q2_b3 = (const float*)d_in[25];

    char* base = (char*)d_ws;
    size_t off = 0;
    auto carve = [&](size_t bytes) -> void* {
        void* p = base + off;
        off = (off + bytes + 255) & ~(size_t)255;
        return p;
    };
    f16* w1dh = (f16*)carve(768 * 32 * 2);   f16* w1dl = (f16*)carve(768 * 32 * 2);
    f16* w2dh = (f16*)carve(768 * 768 * 2);  f16* w2dl = (f16*)carve(768 * 768 * 2);
    f16* aw1h = (f16*)carve(448 * 32 * 2);   f16* aw1l = (f16*)carve(448 * 32 * 2);
    f16* aw2h = (f16*)carve(320 * 448 * 2);  f16* aw2l = (f16*)carve(320 * 448 * 2);
    f16* c1w1h = (f16*)carve(448 * 32 * 2);  f16* c1w1l = (f16*)carve(448 * 32 * 2);
    f16* c1w2h = (f16*)carve(320 * 448 * 2); f16* c1w2l = (f16*)carve(320 * 448 * 2);
    f16* c2w1h = (f16*)carve(448 * 32 * 2);  f16* c2w1l = (f16*)carve(448 * 32 * 2);
    f16* c2w2h = (f16*)carve(320 * 448 * 2); f16* c2w2l = (f16*)carve(320 * 448 * 2);
    float* adec = (float*)carve((size_t)163840 * 3 * 4);
    float* acts = (float*)carve((size_t)163840 * 3 * 4);
    float* qmn  = (float*)carve((size_t)163840 * 4);
    if (off > ws_size) return;  // workspace too small: bail

    auto prep = [&](const float* W, int K, int N, int Kpad, int Npad, f16* h, f16* l) {
        int total = Kpad * Npad;
        int grid = (total + 255) / 256;
        if (grid > 2048) grid = 2048;
        prep_kernel<<<grid, 256, 0, stream>>>(W, K, N, Kpad, Npad, h, l);
    };
    prep(dec_w1, 21, 750, 32, 768, w1dh, w1dl);
    prep(dec_w2, 750, 750, 768, 768, w2dh, w2dl);
    prep(act_w1, 14, 400, 32, 448, aw1h, aw1l);
    prep(act_w2, 400, 300, 448, 320, aw2h, aw2l);
    prep(q1_w1, 14, 400, 32, 448, c1w1h, c1w1l);
    prep(q1_w2, 400, 300, 448, 320, c1w2h, c1w2l);
    prep(q2_w1, 14, 400, 32, 448, c2w1h, c2w1l);
    prep(q2_w2, 400, 300, 448, 320, c2w2h, c2w2l);

    dec_kernel<<<5120, T1, 0, stream>>>(states, noise,
        w1dh, w1dl, dec_b1, w2dh, w2dl, dec_b2, dec_w3, dec_b3, adec);

    aq_kernel<<<5120, T2, 0, stream>>>(states, adec,
        aw1h, aw1l, act_b1, aw2h, aw2l, act_b2, act_w3, act_b3,
        c1w1h, c1w1l, q1_b1, c1w2h, c1w2l, q1_b2, q1_w3, q1_b3,
        c2w1h, c2w1l, q2_b1, c2w2h, c2w2l, q2_b2, q2_w3, q2_b3,
        acts, qmn);

    select_kernel<<<64, 256, 0, stream>>>(qmn, acts, (float*)d_out);
}

// Round 3
// 1213.818 us; speedup vs baseline: 2.2658x; 2.2658x over previous
//
#include <hip/hip_runtime.h>
#include <math.h>

typedef _Float16 f16;
typedef unsigned int u32;
typedef __attribute__((ext_vector_type(8))) _Float16 f16x8;   // 4 VGPR operand frag
typedef __attribute__((ext_vector_type(16))) float f32x16;    // 32x32 accumulator

#define LO_SCALE 4096.0f
#define LO_INV   2.44140625e-4f   // 1/4096

// f16 scaled split: x ~= h + l*(1/4096), |err| ~ 2^-22 |x|
__device__ __forceinline__ void split2f(float x, f16 &h, f16 &l) {
    h = (f16)x;
    l = (f16)((x - (float)h) * LO_SCALE);
}
__device__ __forceinline__ f32x16 mfma32(f16x8 a, f16x8 b, f32x16 c) {
    return __builtin_amdgcn_mfma_f32_32x32x16_f16(a, b, c, 0, 0, 0);
}

// ---------- prep: W [K][N] fp32 row-major -> fragment-ordered hi/lo ----------
// out[((nt*ksteps + ks)*2 + hl)*512 + lane*8 + e]
//   n = nt*32 + (lane&31), k = ks*16 + (lane>>5)*8 + e
// A wave's B-fragment load is then one contiguous 1KB block (coalesced).
__global__ __launch_bounds__(256) void prep_frag(
    const float* __restrict__ W, int K, int N, int ksteps, int ntiles,
    f16* __restrict__ out)
{
    int total = ntiles * ksteps * 512;
    for (int i = blockIdx.x * blockDim.x + threadIdx.x; i < total;
         i += gridDim.x * blockDim.x) {
        int le = i & 511;
        int ks = (i >> 9) % ksteps;
        int nt = i / (512 * ksteps);
        int lane = le >> 3, e = le & 7;
        int n = nt * 32 + (lane & 31);
        int k = ks * 16 + (lane >> 5) * 8 + e;
        float w = (k < K && n < N) ? W[k * N + n] : 0.f;
        f16 h, l; split2f(w, h, l);
        size_t base = ((size_t)(nt * ksteps + ks) * 2) * 512 + le;
        out[base] = h;
        out[base + 512] = l;
    }
}

// ---------- kernel 1: VAE decoder (21 -> 750 -> 750 -> 3, tanh), M=64 ----------
#define DEC_T 512
#define DEC_LDH 392   // 384 + 8 pad; 49 16B-chunks per row (odd -> conflict-free b128)

__global__ __launch_bounds__(512, 2) void dec_kernel(
    const float* __restrict__ states, const float* __restrict__ noise,
    const f16* __restrict__ w1f, const float* __restrict__ b1,
    const f16* __restrict__ w2f, const float* __restrict__ b2,
    const float* __restrict__ w3, const float* __restrict__ b3,
    float* __restrict__ adec)
{
    __shared__ float Xs[64][33];
    __shared__ __align__(16) f16 H1h[64 * DEC_LDH];
    __shared__ __align__(16) f16 H1l[64 * DEC_LDH];
    __shared__ float ow[8][64][3];

    const int tid = threadIdx.x;
    const int lane = tid & 63;
    const int wid = tid >> 6;       // 0..7
    const int l31 = lane & 31;
    const int l5  = lane >> 5;
    const int rowblk = blockIdx.x * 64;

    // X = [state(11) | clip(noise)(10) | 0...] for 64 rows
    for (int idx = tid; idx < 64 * 32; idx += DEC_T) {
        int r = idx >> 5, c = idx & 31;
        int g = rowblk + r;
        float v = 0.f;
        if (c < 11) v = states[(g / 10) * 11 + c];
        else if (c < 21) {
            float z = noise[g * 10 + (c - 11)];
            v = fminf(fmaxf(z, -0.5f), 0.5f);
        }
        Xs[r][c] = v;
    }

    // persistent phase-2 accumulators: 3 n-tiles x 2 m-tiles x (main, cross)
    f32x16 am[3][2], ac[3][2];
    #pragma unroll
    for (int t = 0; t < 3; ++t)
        #pragma unroll
        for (int m = 0; m < 2; ++m)
            #pragma unroll
            for (int r = 0; r < 16; ++r) { am[t][m][r] = 0.f; ac[t][m][r] = 0.f; }

    __syncthreads();

    // two K-halves: phase1 computes H1 cols [h*384,(h+1)*384) into LDS, phase2 consumes
    for (int h = 0; h < 2; ++h) {
        // ---- phase 1: 12 local tiles; wave w does tl=w, and tl=8+w for w<4
        for (int rep = 0; rep < 2; ++rep) {
            if (rep == 1 && wid >= 4) break;
            int tl = (rep == 0) ? wid : 8 + wid;
            int nt = h * 12 + tl;
            #pragma unroll
            for (int m = 0; m < 2; ++m) {
                f32x16 pm, pc;
                #pragma unroll
                for (int r = 0; r < 16; ++r) { pm[r] = 0.f; pc[r] = 0.f; }
                #pragma unroll
                for (int ks = 0; ks < 2; ++ks) {
                    f16x8 xh, xl;
                    #pragma unroll
                    for (int e = 0; e < 8; ++e) {
                        float x = Xs[m * 32 + l31][ks * 16 + l5 * 8 + e];
                        f16 hh, ll; split2f(x, hh, ll);
                        xh[e] = hh; xl[e] = ll;
                    }
                    size_t base = ((size_t)(nt * 2 + ks) * 2) * 512 + lane * 8;
                    f16x8 bh = *(const f16x8*)&w1f[base];
                    f16x8 bl = *(const f16x8*)&w1f[base + 512];
                    pm = mfma32(xh, bh, pm);
                    pc = mfma32(xl, bh, pc);
                    pc = mfma32(xh, bl, pc);
                }
                int col = nt * 32 + l31;
                float bias = (col < 750) ? b1[col] : 0.f;
                int lc = tl * 32 + l31;      // column within this K-half buffer
                #pragma unroll
                for (int r = 0; r < 16; ++r) {
                    int row = m * 32 + (r & 3) + 8 * (r >> 2) + 4 * l5;
                    float v = fmaxf(fmaf(pc[r], LO_INV, pm[r]) + bias, 0.f);
                    f16 hh, ll; split2f(v, hh, ll);
                    H1h[row * DEC_LDH + lc] = hh;
                    H1l[row * DEC_LDH + lc] = ll;
                }
            }
        }
        __syncthreads();

        // ---- phase 2: wave owns n-tiles {wid, wid+8, wid+16}, K-half = 24 ksteps
        for (int ks = 0; ks < 24; ++ks) {
            int ksg = h * 24 + ks;
            const f16x8 ah0 = *(const f16x8*)&H1h[l31 * DEC_LDH + ks * 16 + l5 * 8];
            const f16x8 al0 = *(const f16x8*)&H1l[l31 * DEC_LDH + ks * 16 + l5 * 8];
            const f16x8 ah1 = *(const f16x8*)&H1h[(32 + l31) * DEC_LDH + ks * 16 + l5 * 8];
            const f16x8 al1 = *(const f16x8*)&H1l[(32 + l31) * DEC_LDH + ks * 16 + l5 * 8];
            #pragma unroll
            for (int t = 0; t < 3; ++t) {
                int nt = wid + 8 * t;
                size_t base = ((size_t)(nt * 48 + ksg) * 2) * 512 + lane * 8;
                const f16x8 bh = *(const f16x8*)&w2f[base];
                const f16x8 bl = *(const f16x8*)&w2f[base + 512];
                am[t][0] = mfma32(ah0, bh, am[t][0]);
                ac[t][0] = mfma32(al0, bh, ac[t][0]);
                ac[t][0] = mfma32(ah0, bl, ac[t][0]);
                am[t][1] = mfma32(ah1, bh, am[t][1]);
                ac[t][1] = mfma32(al1, bh, ac[t][1]);
                ac[t][1] = mfma32(ah1, bl, ac[t][1]);
            }
        }
        __syncthreads();
    }

    // fold cross terms into main (frees ac)
    #pragma unroll
    for (int t = 0; t < 3; ++t)
        #pragma unroll
        for (int m = 0; m < 2; ++m)
            #pragma unroll
            for (int r = 0; r < 16; ++r)
                am[t][m][r] = fmaf(ac[t][m][r], LO_INV, am[t][m][r]);

    // phase 3: A = tanh(relu(H2)*W3 + b3), per-lane dot + shuffle reduce
    #pragma unroll
    for (int j = 0; j < 3; ++j) {
        float p0[16], p1[16];
        #pragma unroll
        for (int r = 0; r < 16; ++r) { p0[r] = 0.f; p1[r] = 0.f; }
        #pragma unroll
        for (int t = 0; t < 3; ++t) {
            int col = (wid + 8 * t) * 32 + l31;
            float bias = 0.f, wv = 0.f;
            if (col < 750) { bias = b2[col]; wv = w3[col * 3 + j]; }
            #pragma unroll
            for (int r = 0; r < 16; ++r) {
                p0[r] += fmaxf(am[t][0][r] + bias, 0.f) * wv;
                p1[r] += fmaxf(am[t][1][r] + bias, 0.f) * wv;
            }
        }
        #pragma unroll
        for (int msk = 1; msk < 32; msk <<= 1) {
            #pragma unroll
            for (int r = 0; r < 16; ++r) {
                p0[r] += __shfl_xor(p0[r], msk);
                p1[r] += __shfl_xor(p1[r], msk);
            }
        }
        if (l31 == 0) {
            #pragma unroll
            for (int r = 0; r < 16; ++r) {
                int row = (r & 3) + 8 * (r >> 2) + 4 * l5;
                ow[wid][row][j] = p0[r];
                ow[wid][32 + row][j] = p1[r];
            }
        }
    }
    __syncthreads();
    if (tid < 192) {
        int row = tid / 3, j = tid - row * 3;
        float s = 0.f;
        #pragma unroll
        for (int w = 0; w < 8; ++w) s += ow[w][row][j];
        adec[(rowblk + row) * 3 + j] = tanhf(s + b3[j]);
    }
}

// ---------- kernel 2: actor + twin critics, M=64 ----------
#define AQ_T 640
#define AQ_LDH 456    // 448 + 8 pad; 57 chunks (odd) -> conflict-free

template<int NJ>
__device__ __forceinline__ void mlp_net2(
    const f16* __restrict__ w1f, const float* __restrict__ b1,
    const f16* __restrict__ w2f, const float* __restrict__ b2,
    const float* __restrict__ w3,
    const float (*Xs)[33], f16* H1h, f16* H1l, float (*ow)[64][3], int tid)
{
    const int lane = tid & 63;
    const int wid = tid >> 6;       // 0..9
    const int l31 = lane & 31;
    const int l5  = lane >> 5;

    // phase 1: 14 tiles (448 cols), K=32
    for (int rep = 0; rep < 2; ++rep) {
        if (rep == 1 && wid >= 4) break;
        int t = (rep == 0) ? wid : 10 + wid;
        #pragma unroll
        for (int m = 0; m < 2; ++m) {
            f32x16 pm, pc;
            #pragma unroll
            for (int r = 0; r < 16; ++r) { pm[r] = 0.f; pc[r] = 0.f; }
            #pragma unroll
            for (int ks = 0; ks < 2; ++ks) {
                f16x8 xh, xl;
                #pragma unroll
                for (int e = 0; e < 8; ++e) {
                    float x = Xs[m * 32 + l31][ks * 16 + l5 * 8 + e];
                    f16 hh, ll; split2f(x, hh, ll);
                    xh[e] = hh; xl[e] = ll;
                }
                size_t base = ((size_t)(t * 2 + ks) * 2) * 512 + lane * 8;
                const f16x8 bh = *(const f16x8*)&w1f[base];
                const f16x8 bl = *(const f16x8*)&w1f[base + 512];
                pm = mfma32(xh, bh, pm);
                pc = mfma32(xl, bh, pc);
                pc = mfma32(xh, bl, pc);
            }
            int col = t * 32 + l31;
            float bias = (col < 400) ? b1[col] : 0.f;
            #pragma unroll
            for (int r = 0; r < 16; ++r) {
                int row = m * 32 + (r & 3) + 8 * (r >> 2) + 4 * l5;
                float v = fmaxf(fmaf(pc[r], LO_INV, pm[r]) + bias, 0.f);
                f16 hh, ll; split2f(v, hh, ll);
                H1h[row * AQ_LDH + col] = hh;
                H1l[row * AQ_LDH + col] = ll;
            }
        }
    }
    __syncthreads();

    // phase 2: wave owns n-tile wid (0..9), K=448 (28 ksteps)
    f32x16 am0, ac0, am1, ac1;
    #pragma unroll
    for (int r = 0; r < 16; ++r) { am0[r] = 0.f; ac0[r] = 0.f; am1[r] = 0.f; ac1[r] = 0.f; }
    for (int ks = 0; ks < 28; ++ks) {
        const f16x8 ah0 = *(const f16x8*)&H1h[l31 * AQ_LDH + ks * 16 + l5 * 8];
        const f16x8 al0 = *(const f16x8*)&H1l[l31 * AQ_LDH + ks * 16 + l5 * 8];
        const f16x8 ah1 = *(const f16x8*)&H1h[(32 + l31) * AQ_LDH + ks * 16 + l5 * 8];
        const f16x8 al1 = *(const f16x8*)&H1l[(32 + l31) * AQ_LDH + ks * 16 + l5 * 8];
        size_t base = ((size_t)(wid * 28 + ks) * 2) * 512 + lane * 8;
        const f16x8 bh = *(const f16x8*)&w2f[base];
        const f16x8 bl = *(const f16x8*)&w2f[base + 512];
        am0 = mfma32(ah0, bh, am0);
        ac0 = mfma32(al0, bh, ac0);
        ac0 = mfma32(ah0, bl, ac0);
        am1 = mfma32(ah1, bh, am1);
        ac1 = mfma32(al1, bh, ac1);
        ac1 = mfma32(ah1, bl, ac1);
    }
    #pragma unroll
    for (int r = 0; r < 16; ++r) {
        am0[r] = fmaf(ac0[r], LO_INV, am0[r]);
        am1[r] = fmaf(ac1[r], LO_INV, am1[r]);
    }

    // phase 3
    int col = wid * 32 + l31;
    #pragma unroll
    for (int j = 0; j < NJ; ++j) {
        float p0[16], p1[16];
        #pragma unroll
        for (int r = 0; r < 16; ++r) { p0[r] = 0.f; p1[r] = 0.f; }
        float bias = 0.f, wv = 0.f;
        if (col < 300) { bias = b2[col]; wv = w3[col * NJ + j]; }
        #pragma unroll
        for (int r = 0; r < 16; ++r) {
            p0[r] += fmaxf(am0[r] + bias, 0.f) * wv;
            p1[r] += fmaxf(am1[r] + bias, 0.f) * wv;
        }
        #pragma unroll
        for (int msk = 1; msk < 32; msk <<= 1) {
            #pragma unroll
            for (int r = 0; r < 16; ++r) {
                p0[r] += __shfl_xor(p0[r], msk);
                p1[r] += __shfl_xor(p1[r], msk);
            }
        }
        if (l31 == 0) {
            #pragma unroll
            for (int r = 0; r < 16; ++r) {
                int row = (r & 3) + 8 * (r >> 2) + 4 * l5;
                ow[wid][row][j] = p0[r];
                ow[wid][32 + row][j] = p1[r];
            }
        }
    }
    // caller syncs before reading ow
}

__global__ __launch_bounds__(640, 3) void aq_kernel(
    const float* __restrict__ states, const float* __restrict__ adec,
    const f16* __restrict__ aw1f, const float* __restrict__ ab1,
    const f16* __restrict__ aw2f, const float* __restrict__ ab2,
    const float* __restrict__ aw3, const float* __restrict__ ab3,
    const f16* __restrict__ c1w1f, const float* __restrict__ c1b1,
    const f16* __restrict__ c1w2f, const float* __restrict__ c1b2,
    const float* __restrict__ c1w3, const float* __restrict__ c1b3,
    const f16* __restrict__ c2w1f, const float* __restrict__ c2b1,
    const f16* __restrict__ c2w2f, const float* __restrict__ c2b2,
    const float* __restrict__ c2w3, const float* __restrict__ c2b3,
    float* __restrict__ actions, float* __restrict__ qmin)
{
    __shared__ float Xs[64][33];
    __shared__ __align__(16) f16 H1h[64 * AQ_LDH];
    __shared__ __align__(16) f16 H1l[64 * AQ_LDH];
    __shared__ float ow[10][64][3];
    __shared__ float q1v[64];

    const int tid = threadIdx.x;
    const int rowblk = blockIdx.x * 64;

    // X = [state(11) | a_dec(3) | 0...]
    for (int idx = tid; idx < 64 * 32; idx += AQ_T) {
        int r = idx >> 5, c = idx & 31;
        int g = rowblk + r;
        float v = 0.f;
        if (c < 11) v = states[(g / 10) * 11 + c];
        else if (c < 14) v = adec[g * 3 + (c - 11)];
        Xs[r][c] = v;
    }
    __syncthreads();

    // actor
    mlp_net2<3>(aw1f, ab1, aw2f, ab2, aw3, Xs, H1h, H1l, ow, tid);
    __syncthreads();
    if (tid < 192) {
        int row = tid / 3, j = tid - row * 3;
        float s = 0.f;
        #pragma unroll
        for (int w = 0; w < 10; ++w) s += ow[w][row][j];
        float da = tanhf(s + ab3[j]);
        float ap = Xs[row][11 + j];
        float act = fminf(fmaxf(0.05f * da + ap, -1.f), 1.f);
        actions[(rowblk + row) * 3 + j] = act;
        Xs[row][11 + j] = act;
    }
    __syncthreads();

    // q1
    mlp_net2<1>(c1w1f, c1b1, c1w2f, c1b2, c1w3, Xs, H1h, H1l, ow, tid);
    __syncthreads();
    if (tid < 64) {
        float s = 0.f;
        #pragma unroll
        for (int w = 0; w < 10; ++w) s += ow[w][tid][0];
        q1v[tid] = s + c1b3[0];
    }
    __syncthreads();

    // q2 + min
    mlp_net2<1>(c2w1f, c2b1, c2w2f, c2b2, c2w3, Xs, H1h, H1l, ow, tid);
    __syncthreads();
    if (tid < 64) {
        float s = 0.f;
        #pragma unroll
        for (int w = 0; w < 10; ++w) s += ow[w][tid][0];
        qmin[rowblk + tid] = fminf(q1v[tid], s + c2b3[0]);
    }
}

// ---------- kernel 3: per-state argmax (first max) + gather ----------
__global__ __launch_bounds__(256) void select_kernel(
    const float* __restrict__ qmin, const float* __restrict__ actions,
    float* __restrict__ out)
{
    int s = blockIdx.x * blockDim.x + threadIdx.x;
    if (s >= 16384) return;
    const float* q = qmin + s * 10;
    int best = 0;
    float bq = q[0];
    #pragma unroll
    for (int i = 1; i < 10; ++i) {
        float v = q[i];
        if (v > bq) { bq = v; best = i; }
    }
    const float* a = actions + (size_t)(s * 10 + best) * 3;
    out[s * 3 + 0] = a[0];
    out[s * 3 + 1] = a[1];
    out[s * 3 + 2] = a[2];
}

extern "C" void kernel_launch(void* const* d_in, const int* in_sizes, int n_in,
                              void* d_out, int out_size, void* d_ws, size_t ws_size,
                              hipStream_t stream)
{
    const float* states = (const float*)d_in[0];
    const float* noise  = (const float*)d_in[1];
    const float* dec_w1 = (const float*)d_in[2];
    const float* dec_b1 = (const float*)d_in[3];
    const float* dec_w2 = (const float*)d_in[4];
    const float* dec_b2 = (const float*)d_in[5];
    const float* dec_w3 = (const float*)d_in[6];
    const float* dec_b3 = (const float*)d_in[7];
    const float* act_w1 = (const float*)d_in[8];
    const float* act_b1 = (const float*)d_in[9];
    const float* act_w2 = (const float*)d_in[10];
    const float* act_b2 = (const float*)d_in[11];
    const float* act_w3 = (const float*)d_in[12];
    const float* act_b3 = (const float*)d_in[13];
    const float* q1_w1 = (const float*)d_in[14];
    const float* q1_b1 = (const float*)d_in[15];
    const float* q1_w2 = (const float*)d_in[16];
    const float* q1_b2 = (const float*)d_in[17];
    const float* q1_w3 = (const float*)d_in[18];
    const float* q1_b3 = (const float*)d_in[19];
    const float* q2_w1 = (const float*)d_in[20];
    const float* q2_b1 = (const float*)d_in[21];
    const float* q2_w2 = (const float*)d_in[22];
    const float* q2_b2 = (const float*)d_in[23];
    const float* q2_w3 = (const float*)d_in[24];
    const float* q2_b3 = (const float*)d_in[25];

    char* base = (char*)d_ws;
    size_t off = 0;
    auto carve = [&](size_t bytes) -> void* {
        void* p = base + off;
        off = (off + bytes + 255) & ~(size_t)255;
        return p;
    };
    // fragment arrays: ntiles*ksteps*1024 f16 each
    f16* w1df = (f16*)carve((size_t)24 * 2 * 1024 * 2);
    f16* w2df = (f16*)carve((size_t)24 * 48 * 1024 * 2);
    f16* aw1f = (f16*)carve((size_t)14 * 2 * 1024 * 2);
    f16* aw2f = (f16*)carve((size_t)10 * 28 * 1024 * 2);
    f16* c1w1f = (f16*)carve((size_t)14 * 2 * 1024 * 2);
    f16* c1w2f = (f16*)carve((size_t)10 * 28 * 1024 * 2);
    f16* c2w1f = (f16*)carve((size_t)14 * 2 * 1024 * 2);
    f16* c2w2f = (f16*)carve((size_t)10 * 28 * 1024 * 2);
    float* adec = (float*)carve((size_t)163840 * 3 * 4);
    float* acts = (float*)carve((size_t)163840 * 3 * 4);
    float* qmn  = (float*)carve((size_t)163840 * 4);
    if (off > ws_size) return;  // workspace too small: bail

    auto prep = [&](const float* W, int K, int N, int ksteps, int ntiles, f16* out) {
        int total = ntiles * ksteps * 512;
        int grid = (total + 255) / 256;
        if (grid > 2048) grid = 2048;
        prep_frag<<<grid, 256, 0, stream>>>(W, K, N, ksteps, ntiles, out);
    };
    prep(dec_w1, 21, 750, 2, 24, w1df);
    prep(dec_w2, 750, 750, 48, 24, w2df);
    prep(act_w1, 14, 400, 2, 14, aw1f);
    prep(act_w2, 400, 300, 28, 10, aw2f);
    prep(q1_w1, 14, 400, 2, 14, c1w1f);
    prep(q1_w2, 400, 300, 28, 10, c1w2f);
    prep(q2_w1, 14, 400, 2, 14, c2w1f);
    prep(q2_w2, 400, 300, 28, 10, c2w2f);

    dec_kernel<<<2560, DEC_T, 0, stream>>>(states, noise,
        w1df, dec_b1, w2df, dec_b2, dec_w3, dec_b3, adec);

    aq_kernel<<<2560, AQ_T, 0, stream>>>(states, adec,
        aw1f, act_b1, aw2f, act_b2, act_w3, act_b3,
        c1w1f, q1_b1, c1w2f, q1_b2, q1_w3, q1_b3,
        c2w1f, q2_b1, c2w2f, q2_b2, q2_w3, q2_b3,
        acts, qmn);

    select_kernel<<<64, 256, 0, stream>>>(qmn, acts, (float*)d_out);
}